// Round 5
// baseline (273.779 us; speedup 1.0000x reference)
//
#include <hip/hip_runtime.h>
#include <stdint.h>

#define HW    1024          // H*W
#define NK    2048          // codes per codebook
#define DR    128           // reduced dim
#define NSTG  32            // stages of 64 codes
#define BIAS  1536.0f       // score positivity bias (scores stay in one binade [1024,2048))

typedef __attribute__((ext_vector_type(4))) float f32x4;
typedef __attribute__((ext_vector_type(2))) float f32x2;
typedef __attribute__((ext_vector_type(2))) long i64x2;
typedef __attribute__((ext_vector_type(8))) int i32x8;
typedef unsigned int u32;
typedef unsigned long long u64;

union B8 { uint4 q[2]; i32x8 v; };

__device__ __forceinline__ long pack8_fp8(const float* x) {
  int lo = 0, hi = 0;
  lo = __builtin_amdgcn_cvt_pk_fp8_f32(x[0], x[1], lo, false);
  lo = __builtin_amdgcn_cvt_pk_fp8_f32(x[2], x[3], lo, true);
  hi = __builtin_amdgcn_cvt_pk_fp8_f32(x[4], x[5], hi, false);
  hi = __builtin_amdgcn_cvt_pk_fp8_f32(x[6], x[7], hi, true);
  return (long)(u32)lo | ((long)hi << 32);
}

// ---- prep (fused): e2h = BIAS - 2048*sum(e^2); esw = K128-fragment-order fp8*4096;
//      efp8 = row-major fp8*4096 (epilogue gather) ----
__global__ void k_prep(const float* __restrict__ emb, char* __restrict__ esw,
                       char* __restrict__ efp8, float* __restrict__ e2h) {
  const int tid = threadIdx.x;
  const int row = blockIdx.x * 32 + (tid >> 3);   // 0..8191
  const int seg = tid & 7;                        // 16-dim segment
  const int c = row >> 11, code = row & 2047;
  const float* src = emb + (size_t)row * DR + seg * 16;
  float v[16];
#pragma unroll
  for (int i = 0; i < 16; i += 4) {
    float4 t = *(const float4*)(src + i);
    v[i] = t.x; v[i+1] = t.y; v[i+2] = t.z; v[i+3] = t.w;
  }
  float s2 = 0.f;
#pragma unroll
  for (int i = 0; i < 16; ++i) s2 += v[i] * v[i];
  s2 += __shfl_down(s2, 4, 64);
  s2 += __shfl_down(s2, 2, 64);
  s2 += __shfl_down(s2, 1, 64);
  if (seg == 0) e2h[row] = BIAS - 2048.0f * s2;

  float vs[16];
#pragma unroll
  for (int i = 0; i < 16; ++i) vs[i] = v[i] * 4096.0f;
  i64x2 p; p.x = pack8_fp8(vs); p.y = pack8_fp8(vs + 8);
  *(i64x2*)(efp8 + (size_t)row * DR + seg * 16) = p;   // row-major fp8 image

  // fragment-order: this thread's 16 dims are one (lane,plane) 16B slot
  const int stage = code >> 6, cb = (code >> 4) & 3;
  const int g = seg >> 1, plane = seg & 1;
  const int lane = g * 16 + (code & 15);
  char* dst = esw + ((size_t)(c * 32 + stage) * 8192) + cb * 2048 + plane * 1024 + lane * 16;
  *(i64x2*)dst = p;
}

// ---- main: MX fp8 K=128 GEMM-argmax, code-split across wave pairs, no LDS staging ----
__device__ __forceinline__ void load_stage(const char* bp, const float* e2p, int S,
                                           B8 Bq[4], float e2f[4]) {
#pragma unroll
  for (int cb = 0; cb < 4; ++cb) {
    const char* p = bp + (size_t)S * 8192 + cb * 2048;
    Bq[cb].q[0] = *(const uint4*)p;
    Bq[cb].q[1] = *(const uint4*)(p + 1024);
    e2f[cb] = e2p[S * 64 + cb * 16];
  }
}

__device__ __forceinline__ void compute_stage(int s, int r, const i32x8 A[4],
                                              const B8 Bq[4], const float e2f[4],
                                              u32 kk[4][4]) {
#pragma unroll
  for (int cb = 0; cb < 4; ++cb) {
    const float eh = e2f[cb];
    f32x4 ci = {eh, eh, eh, eh};
    const u32 inv = 2047u - (u32)(s * 64 + cb * 16 + r);
#pragma unroll
    for (int t2 = 0; t2 < 4; ++t2) {
      f32x4 ac = __builtin_amdgcn_mfma_scale_f32_16x16x128_f8f6f4(
          A[t2], Bq[cb].v, ci, 0, 0, 0, 0x7F7F7F7F, 0, 0x7F7F7F7F);
#pragma unroll
      for (int j = 0; j < 4; ++j) {
        u32 k = (__float_as_uint(ac[j]) & 0xFFFFF800u) | inv;
        kk[t2][j] = k > kk[t2][j] ? k : kk[t2][j];
      }
    }
  }
}

__launch_bounds__(256, 4)
__global__ void k_main(const float* __restrict__ lat,
                       const char* __restrict__ esw,
                       const char* __restrict__ efp8,
                       const float* __restrict__ e2h,
                       float* __restrict__ outq,
                       float* __restrict__ partials) {
  __shared__ u32 kbuf[4][64];
  __shared__ int idxs[128];
  __shared__ float wsum[4];

  const int tid = threadIdx.x, wave = tid >> 6, lane = tid & 63;
  const int r = lane & 15, g = lane >> 4;
  const int pair = wave >> 1;          // token half: 0 -> tokens 0-63, 1 -> 64-127
  const int half = wave & 1;           // stage half: 0 -> stages 0-15, 1 -> 16-31
  const int bid = blockIdx.x;
  const int c = bid >> 8, b = (bid >> 3) & 31, hw0 = (bid & 7) * 128;

  const char* bp   = esw + (size_t)c * (NSTG * 8192) + lane * 16;
  const float* e2p = e2h + c * NK + r;
  const int sbase = half * 16;

  // issue stage-sbase B/e2 loads first (L2), then A loads (HBM) under them
  B8 B0[4], B1[4];
  float E0[4], E1[4];
  load_stage(bp, e2p, sbase, B0, E0);

  // A: 64 tokens/wave as 4 tiles; lane (r,g) holds dims g*32..g*32+31, fp8-packed
  i32x8 A[4];
  {
    const float* xb = lat + ((size_t)(b * 512 + c + g * 32)) * HW + hw0 + pair * 64 + r;
#pragma unroll
    for (int t2 = 0; t2 < 4; ++t2) {
      float xs[32];
#pragma unroll
      for (int j = 0; j < 32; ++j) xs[j] = xb[(size_t)j * HW + t2 * 16];
      union { long l[4]; i32x8 v; } u;
#pragma unroll
      for (int q = 0; q < 4; ++q) u.l[q] = pack8_fp8(xs + q * 8);
      A[t2] = u.v;
    }
  }

  u32 kk[4][4];
#pragma unroll
  for (int t2 = 0; t2 < 4; ++t2)
#pragma unroll
    for (int j = 0; j < 4; ++j) kk[t2][j] = 0u;

  // register-double-buffered loop over this wave's 16 stages: no barriers
  for (int t = 0; t < 8; ++t) {
    const int s0 = sbase + 2 * t;
    load_stage(bp, e2p, s0 + 1, B1, E1);
    compute_stage(s0, r, A, B0, E0, kk);
    if (t < 7) load_stage(bp, e2p, s0 + 2, B0, E0);
    compute_stage(s0 + 1, r, A, B1, E1, kk);
  }

  // cross-lane key-max over the 16 code lanes; index in low 11 bits
#pragma unroll
  for (int t2 = 0; t2 < 4; ++t2)
#pragma unroll
    for (int j = 0; j < 4; ++j) {
      u32 k = kk[t2][j];
#pragma unroll
      for (int m = 1; m < 16; m <<= 1) {
        u32 o = (u32)__shfl_xor((int)k, m, 64);
        if (o > k) k = o;
      }
      if (r == 0) kbuf[wave][t2 * 16 + g * 4 + j] = k;
    }
  __syncthreads();

  // combine the two stage-halves per token
  if (tid < 128) {
    const int p = tid >> 6, t = tid & 63;
    u32 ka = kbuf[2 * p][t], kb = kbuf[2 * p + 1][t];
    u32 k = ka > kb ? ka : kb;
    idxs[tid] = 2047 - (int)(k & 2047u);
  }
  __syncthreads();

  // epilogue: fp8 gather (16B/row-seg), dequant, write, exact-f32 loss
  const int q5 = tid & 31, dg = tid >> 5;       // 32 token-quads x 8 dim-groups of 16
  const int tok0 = q5 * 4;
  const int code0 = idxs[tok0], code1 = idxs[tok0 + 1], code2 = idxs[tok0 + 2], code3 = idxs[tok0 + 3];
  const char* eb = efp8 + (size_t)c * NK * DR + dg * 16;
  uint4 e0 = *(const uint4*)(eb + (size_t)code0 * DR);
  uint4 e1 = *(const uint4*)(eb + (size_t)code1 * DR);
  uint4 e2v = *(const uint4*)(eb + (size_t)code2 * DR);
  uint4 e3 = *(const uint4*)(eb + (size_t)code3 * DR);
  const float* xrow = lat  + ((size_t)(b * 512 + c + dg * 16)) * HW + hw0 + tok0;
  float*       orow = outq + ((size_t)(b * 512 + c * DR + dg * 16)) * HW + hw0 + tok0;
  const float SINV = 1.0f / 4096.0f;
  float lossacc = 0.f;

#define WORD(v, w) ((w) == 0 ? (v).x : (w) == 1 ? (v).y : (w) == 2 ? (v).z : (v).w)
#pragma unroll
  for (int w = 0; w < 4; ++w) {
    f32x2 lo0 = __builtin_amdgcn_cvt_pk_f32_fp8((int)WORD(e0, w), false);
    f32x2 hi0 = __builtin_amdgcn_cvt_pk_f32_fp8((int)WORD(e0, w), true);
    f32x2 lo1 = __builtin_amdgcn_cvt_pk_f32_fp8((int)WORD(e1, w), false);
    f32x2 hi1 = __builtin_amdgcn_cvt_pk_f32_fp8((int)WORD(e1, w), true);
    f32x2 lo2 = __builtin_amdgcn_cvt_pk_f32_fp8((int)WORD(e2v, w), false);
    f32x2 hi2 = __builtin_amdgcn_cvt_pk_f32_fp8((int)WORD(e2v, w), true);
    f32x2 lo3 = __builtin_amdgcn_cvt_pk_f32_fp8((int)WORD(e3, w), false);
    f32x2 hi3 = __builtin_amdgcn_cvt_pk_f32_fp8((int)WORD(e3, w), true);
    float f0[4] = {lo0.x, lo0.y, hi0.x, hi0.y};
    float f1[4] = {lo1.x, lo1.y, hi1.x, hi1.y};
    float f2[4] = {lo2.x, lo2.y, hi2.x, hi2.y};
    float f3[4] = {lo3.x, lo3.y, hi3.x, hi3.y};
#pragma unroll
    for (int dd = 0; dd < 4; ++dd) {
      int d = w * 4 + dd;
      float4 x = *(const float4*)(xrow + (size_t)d * HW);
      float q0 = f0[dd] * SINV, q1 = f1[dd] * SINV, q2 = f2[dd] * SINV, q3 = f3[dd] * SINV;
      float d0 = q0 - x.x, d1 = q1 - x.y, d2 = q2 - x.z, d3 = q3 - x.w;
      lossacc += d0 * d0 + d1 * d1 + d2 * d2 + d3 * d3;
      float4 qv = {q0, q1, q2, q3};
      *(float4*)(orow + (size_t)d * HW) = qv;
    }
  }
#undef WORD

#pragma unroll
  for (int off = 32; off; off >>= 1) lossacc += __shfl_down(lossacc, off, 64);
  if (lane == 0) wsum[wave] = lossacc;
  __syncthreads();
  if (tid == 0) partials[bid] = wsum[0] + wsum[1] + wsum[2] + wsum[3];
}

// ---- final: reduce 1024 partials -> vq_loss ----
__global__ void k_final(const float* __restrict__ partials, float* __restrict__ out_scalar) {
  __shared__ float ws[4];
  int tid = threadIdx.x;
  float s = partials[tid] + partials[tid + 256] + partials[tid + 512] + partials[tid + 768];
#pragma unroll
  for (int off = 32; off; off >>= 1) s += __shfl_down(s, off, 64);
  if ((tid & 63) == 0) ws[tid >> 6] = s;
  __syncthreads();
  if (tid == 0) out_scalar[0] = (ws[0] + ws[1] + ws[2] + ws[3]) * (1.25f / 4194304.0f);
}

extern "C" void kernel_launch(void* const* d_in, const int* in_sizes, int n_in,
                              void* d_out, int out_size, void* d_ws, size_t ws_size,
                              hipStream_t stream) {
  const float* lat = (const float*)d_in[0];   // [32,512,32,32] f32
  const float* emb = (const float*)d_in[1];   // [4,2048,128] f32
  float* out = (float*)d_out;                 // quantized (16777216) + loss (1)

  char*  esw      = (char*)d_ws;                                   // 1 MB fragment-order fp8
  char*  efp8     = (char*)d_ws + (1u << 20);                      // 1 MB row-major fp8
  float* e2h      = (float*)((char*)d_ws + (2u << 20));            // 32 KB
  float* partials = (float*)((char*)d_ws + (2u << 20) + 32768u);   // 4 KB

  k_prep <<<dim3(256),  dim3(256), 0, stream>>>(emb, esw, efp8, e2h);
  k_main <<<dim3(1024), dim3(256), 0, stream>>>(lat, esw, efp8, e2h, out, partials);
  k_final<<<dim3(1),    dim3(256), 0, stream>>>(partials, out + 16777216);
}

// Round 6
// 71.076 us; speedup vs baseline: 3.8519x; 3.8519x over previous
//
#include <hip/hip_runtime.h>
#include <stdint.h>

#define HW    1024          // H*W
#define NK    2048          // codes per codebook
#define DR    128           // reduced dim
#define NSTG  32            // stages of 64 codes
#define BIAS  1536.0f       // score positivity bias (scores stay in one binade [1024,2048))

typedef __attribute__((ext_vector_type(4))) float f32x4;
typedef __attribute__((ext_vector_type(2))) float f32x2;
typedef __attribute__((ext_vector_type(2))) long i64x2;
typedef __attribute__((ext_vector_type(8))) int i32x8;
typedef unsigned int u32;
typedef unsigned long long u64;

__device__ __forceinline__ long pack8_fp8(const float* x) {
  int lo = 0, hi = 0;
  lo = __builtin_amdgcn_cvt_pk_fp8_f32(x[0], x[1], lo, false);
  lo = __builtin_amdgcn_cvt_pk_fp8_f32(x[2], x[3], lo, true);
  hi = __builtin_amdgcn_cvt_pk_fp8_f32(x[4], x[5], hi, false);
  hi = __builtin_amdgcn_cvt_pk_fp8_f32(x[6], x[7], hi, true);
  return (long)(u32)lo | ((long)hi << 32);
}

// ---- prep (fused): e2h = BIAS - 2048*sum(e^2); esw = K128-fragment-order fp8*4096;
//      efp8 = row-major fp8*4096 (epilogue gather) ----
__global__ void k_prep(const float* __restrict__ emb, char* __restrict__ esw,
                       char* __restrict__ efp8, float* __restrict__ e2h) {
  const int tid = threadIdx.x;
  const int row = blockIdx.x * 32 + (tid >> 3);   // 0..8191
  const int seg = tid & 7;                        // 16-dim segment
  const int c = row >> 11, code = row & 2047;
  const float* src = emb + (size_t)row * DR + seg * 16;
  float v[16];
#pragma unroll
  for (int i = 0; i < 16; i += 4) {
    float4 t = *(const float4*)(src + i);
    v[i] = t.x; v[i+1] = t.y; v[i+2] = t.z; v[i+3] = t.w;
  }
  float s2 = 0.f;
#pragma unroll
  for (int i = 0; i < 16; ++i) s2 += v[i] * v[i];
  s2 += __shfl_down(s2, 4, 64);
  s2 += __shfl_down(s2, 2, 64);
  s2 += __shfl_down(s2, 1, 64);
  if (seg == 0) e2h[row] = BIAS - 2048.0f * s2;

  float vs[16];
#pragma unroll
  for (int i = 0; i < 16; ++i) vs[i] = v[i] * 4096.0f;
  i64x2 p; p.x = pack8_fp8(vs); p.y = pack8_fp8(vs + 8);
  *(i64x2*)(efp8 + (size_t)row * DR + seg * 16) = p;   // row-major fp8 image

  // fragment-order: this thread's 16 dims are one (lane,plane) 16B slot
  const int stage = code >> 6, cb = (code >> 4) & 3;
  const int g = seg >> 1, plane = seg & 1;
  const int lane = g * 16 + (code & 15);
  char* dst = esw + ((size_t)(c * 32 + stage) * 8192) + cb * 2048 + plane * 1024 + lane * 16;
  *(i64x2*)dst = p;
}

// ---- main: MX fp8 K=128 GEMM-argmax, code-split across wave pairs, lean registers ----
// chunk = 32 codes (half a stage): B = 2 x i32x8 (16 VGPR), double-buffered -> 32 VGPR
__device__ __forceinline__ void load_chunk(const char* bp, const float* e2p, int ch,
                                           i32x8& Ba, i32x8& Bb, float& ea, float& eb) {
  const char* p = bp + (size_t)ch * 4096;
  union { uint4 q[2]; i32x8 v; } ua, ub;
  ua.q[0] = *(const uint4*)p;
  ua.q[1] = *(const uint4*)(p + 1024);
  ub.q[0] = *(const uint4*)(p + 2048);
  ub.q[1] = *(const uint4*)(p + 3072);
  Ba = ua.v; Bb = ub.v;
  ea = e2p[ch * 32];
  eb = e2p[ch * 32 + 16];
}

__device__ __forceinline__ void compute_chunk(int ch, int r, const i32x8 A[4],
                                              const i32x8& Ba, const i32x8& Bb,
                                              float ea, float eb, u32 kk[4][4]) {
  const u32 inva = 2047u - (u32)(ch * 32 + r);
  const u32 invb = inva - 16u;
  f32x4 cia = {ea, ea, ea, ea}, cib = {eb, eb, eb, eb};
#pragma unroll
  for (int t2 = 0; t2 < 4; ++t2) {
    f32x4 a1 = __builtin_amdgcn_mfma_scale_f32_16x16x128_f8f6f4(
        A[t2], Ba, cia, 0, 0, 0, 0x7F7F7F7F, 0, 0x7F7F7F7F);
#pragma unroll
    for (int j = 0; j < 4; ++j) {
      u32 k = (__float_as_uint(a1[j]) & 0xFFFFF800u) | inva;
      kk[t2][j] = k > kk[t2][j] ? k : kk[t2][j];
    }
    f32x4 a2 = __builtin_amdgcn_mfma_scale_f32_16x16x128_f8f6f4(
        A[t2], Bb, cib, 0, 0, 0, 0x7F7F7F7F, 0, 0x7F7F7F7F);
#pragma unroll
    for (int j = 0; j < 4; ++j) {
      u32 k = (__float_as_uint(a2[j]) & 0xFFFFF800u) | invb;
      kk[t2][j] = k > kk[t2][j] ? k : kk[t2][j];
    }
  }
}

__launch_bounds__(256, 4)
__global__ void k_main(const float* __restrict__ lat,
                       const char* __restrict__ esw,
                       const char* __restrict__ efp8,
                       const float* __restrict__ e2h,
                       float* __restrict__ outq,
                       float* __restrict__ partials) {
  __shared__ u32 kbuf[4][64];
  __shared__ float x2buf[128];
  __shared__ int idxs[128];
  __shared__ float wsum[4];

  const int tid = threadIdx.x, wave = tid >> 6, lane = tid & 63;
  const int r = lane & 15, g = lane >> 4;
  const int pair = wave >> 1;          // token half: 0 -> tokens 0-63, 1 -> 64-127
  const int half = wave & 1;           // code half: 0 -> chunks 0-31, 1 -> 32-63
  const int bid = blockIdx.x;
  const int c = bid >> 8, b = (bid >> 3) & 31, hw0 = (bid & 7) * 128;

  const char* bp   = esw + (size_t)c * (NSTG * 8192) + lane * 16;
  const float* e2p = e2h + c * NK + r;
  const int ch0 = half * 32;

  // issue first B chunk (L2), then A loads (HBM) under it
  i32x8 Ba0, Bb0, Ba1, Bb1;
  float ea0, eb0, ea1, eb1;
  load_chunk(bp, e2p, ch0, Ba0, Bb0, ea0, eb0);

  // A: 64 tokens/wave as 4 tiles; lane (r,g) holds dims g*32..g*32+31, fp8-packed.
  // Also compute exact f32 ||x||^2 per token (for the key-based loss).
  i32x8 A[4];
  {
    const float* xb = lat + ((size_t)(b * 512 + c + g * 32)) * HW + hw0 + pair * 64 + r;
#pragma unroll
    for (int t2 = 0; t2 < 4; ++t2) {
      float xs[32];
#pragma unroll
      for (int j = 0; j < 32; ++j) xs[j] = xb[(size_t)j * HW + t2 * 16];
      union { long l[4]; i32x8 v; } u;
#pragma unroll
      for (int q = 0; q < 4; ++q) u.l[q] = pack8_fp8(xs + q * 8);
      A[t2] = u.v;
      float s = 0.f;
#pragma unroll
      for (int j = 0; j < 32; ++j) s += xs[j] * xs[j];
      s += __shfl_xor(s, 16, 64);
      s += __shfl_xor(s, 32, 64);        // all 4 g-lanes now hold token (pair*64+t2*16+r)'s ||x||^2
      if (half == 0 && g == 0) x2buf[pair * 64 + t2 * 16 + r] = s;
    }
  }

  u32 kk[4][4];
#pragma unroll
  for (int t2 = 0; t2 < 4; ++t2)
#pragma unroll
    for (int j = 0; j < 4; ++j) kk[t2][j] = 0u;

  // register-double-buffered loop over this wave's 32 chunks: no barriers
  for (int t = 0; t < 16; ++t) {
    const int s0 = ch0 + 2 * t;
    load_chunk(bp, e2p, s0 + 1, Ba1, Bb1, ea1, eb1);
    compute_chunk(s0, r, A, Ba0, Bb0, ea0, eb0, kk);
    if (t < 15) load_chunk(bp, e2p, s0 + 2, Ba0, Bb0, ea0, eb0);
    compute_chunk(s0 + 1, r, A, Ba1, Bb1, ea1, eb1, kk);
  }

  // cross-lane key-max over the 16 code lanes; index in low 11 bits
#pragma unroll
  for (int t2 = 0; t2 < 4; ++t2)
#pragma unroll
    for (int j = 0; j < 4; ++j) {
      u32 k = kk[t2][j];
#pragma unroll
      for (int m = 1; m < 16; m <<= 1) {
        u32 o = (u32)__shfl_xor((int)k, m, 64);
        if (o > k) k = o;
      }
      if (r == 0) kbuf[wave][t2 * 16 + g * 4 + j] = k;
    }
  __syncthreads();

  // combine code halves per token; loss from key: 2048*dist = (BIAS - score) + 2048*||x||^2
  float lossv = 0.f;
  if (tid < 128) {
    const int p = tid >> 6, m = tid & 63;
    u32 ka = kbuf[2 * p][m], kb = kbuf[2 * p + 1][m];
    u32 k = ka > kb ? ka : kb;
    idxs[tid] = 2047 - (int)(k & 2047u);
    float kf = __uint_as_float(k & 0xFFFFF800u);
    lossv = (BIAS - kf) + 2048.0f * x2buf[tid];
  }
#pragma unroll
  for (int off = 32; off; off >>= 1) lossv += __shfl_down(lossv, off, 64);
  if (lane == 0) wsum[wave] = lossv;
  __syncthreads();
  if (tid == 0) partials[bid] = wsum[0] + wsum[1] + wsum[2] + wsum[3];

  // epilogue: fp8 gather (16B/row-seg), dequant, coalesced write (no lat re-read)
  const int q5 = tid & 31, dg = tid >> 5;       // 32 token-quads x 8 dim-groups of 16
  const int tok0 = q5 * 4;
  const int code0 = idxs[tok0], code1 = idxs[tok0 + 1], code2 = idxs[tok0 + 2], code3 = idxs[tok0 + 3];
  const char* eb = efp8 + (size_t)c * NK * DR + dg * 16;
  uint4 e0 = *(const uint4*)(eb + (size_t)code0 * DR);
  uint4 e1 = *(const uint4*)(eb + (size_t)code1 * DR);
  uint4 e2v = *(const uint4*)(eb + (size_t)code2 * DR);
  uint4 e3 = *(const uint4*)(eb + (size_t)code3 * DR);
  float* orow = outq + ((size_t)(b * 512 + c * DR + dg * 16)) * HW + hw0 + tok0;
  const float SINV = 1.0f / 4096.0f;

#define WORD(v, w) ((w) == 0 ? (v).x : (w) == 1 ? (v).y : (w) == 2 ? (v).z : (v).w)
#pragma unroll
  for (int w = 0; w < 4; ++w) {
    f32x2 lo0 = __builtin_amdgcn_cvt_pk_f32_fp8((int)WORD(e0, w), false);
    f32x2 hi0 = __builtin_amdgcn_cvt_pk_f32_fp8((int)WORD(e0, w), true);
    f32x2 lo1 = __builtin_amdgcn_cvt_pk_f32_fp8((int)WORD(e1, w), false);
    f32x2 hi1 = __builtin_amdgcn_cvt_pk_f32_fp8((int)WORD(e1, w), true);
    f32x2 lo2 = __builtin_amdgcn_cvt_pk_f32_fp8((int)WORD(e2v, w), false);
    f32x2 hi2 = __builtin_amdgcn_cvt_pk_f32_fp8((int)WORD(e2v, w), true);
    f32x2 lo3 = __builtin_amdgcn_cvt_pk_f32_fp8((int)WORD(e3, w), false);
    f32x2 hi3 = __builtin_amdgcn_cvt_pk_f32_fp8((int)WORD(e3, w), true);
    float f0[4] = {lo0.x, lo0.y, hi0.x, hi0.y};
    float f1[4] = {lo1.x, lo1.y, hi1.x, hi1.y};
    float f2[4] = {lo2.x, lo2.y, hi2.x, hi2.y};
    float f3[4] = {lo3.x, lo3.y, hi3.x, hi3.y};
#pragma unroll
    for (int dd = 0; dd < 4; ++dd) {
      int d = w * 4 + dd;
      float4 qv = {f0[dd] * SINV, f1[dd] * SINV, f2[dd] * SINV, f3[dd] * SINV};
      *(float4*)(orow + (size_t)d * HW) = qv;
    }
  }
#undef WORD
}

// ---- final: reduce 1024 partials -> vq_loss (partials carry 2048*dist) ----
__global__ void k_final(const float* __restrict__ partials, float* __restrict__ out_scalar) {
  __shared__ float ws[4];
  int tid = threadIdx.x;
  float s = partials[tid] + partials[tid + 256] + partials[tid + 512] + partials[tid + 768];
#pragma unroll
  for (int off = 32; off; off >>= 1) s += __shfl_down(s, off, 64);
  if ((tid & 63) == 0) ws[tid >> 6] = s;
  __syncthreads();
  if (tid == 0) out_scalar[0] = (ws[0] + ws[1] + ws[2] + ws[3]) * (1.25f / 8589934592.0f);
}

extern "C" void kernel_launch(void* const* d_in, const int* in_sizes, int n_in,
                              void* d_out, int out_size, void* d_ws, size_t ws_size,
                              hipStream_t stream) {
  const float* lat = (const float*)d_in[0];   // [32,512,32,32] f32
  const float* emb = (const float*)d_in[1];   // [4,2048,128] f32
  float* out = (float*)d_out;                 // quantized (16777216) + loss (1)

  char*  esw      = (char*)d_ws;                                   // 1 MB fragment-order fp8
  char*  efp8     = (char*)d_ws + (1u << 20);                      // 1 MB row-major fp8
  float* e2h      = (float*)((char*)d_ws + (2u << 20));            // 32 KB
  float* partials = (float*)((char*)d_ws + (2u << 20) + 32768u);   // 4 KB

  k_prep <<<dim3(256),  dim3(256), 0, stream>>>(emb, esw, efp8, e2h);
  k_main <<<dim3(1024), dim3(256), 0, stream>>>(lat, esw, efp8, e2h, out, partials);
  k_final<<<dim3(1),    dim3(256), 0, stream>>>(partials, out + 16777216);
}

// Round 7
// 63.554 us; speedup vs baseline: 4.3078x; 1.1183x over previous
//
#include <hip/hip_runtime.h>
#include <stdint.h>

#define HW    1024          // H*W
#define NK    2048          // codes per codebook
#define DR    128           // reduced dim
#define NSTG  32            // stages of 64 codes
#define BIAS  1536.0f       // score positivity bias (scores stay in one binade [1024,2048))

typedef __attribute__((ext_vector_type(4))) float f32x4;
typedef __attribute__((ext_vector_type(2))) float f32x2;
typedef __attribute__((ext_vector_type(2))) long i64x2;
typedef __attribute__((ext_vector_type(8))) int i32x8;
typedef unsigned int u32;
typedef unsigned long long u64;

__device__ __forceinline__ long pack8_fp8(const float* x) {
  int lo = 0, hi = 0;
  lo = __builtin_amdgcn_cvt_pk_fp8_f32(x[0], x[1], lo, false);
  lo = __builtin_amdgcn_cvt_pk_fp8_f32(x[2], x[3], lo, true);
  hi = __builtin_amdgcn_cvt_pk_fp8_f32(x[4], x[5], hi, false);
  hi = __builtin_amdgcn_cvt_pk_fp8_f32(x[6], x[7], hi, true);
  return (long)(u32)lo | ((long)hi << 32);
}

// ---- prep (fused): e2h = BIAS - 2048*sum(e^2); esw = K128-fragment-order fp8*4096;
//      efp8 = row-major fp8*4096 (epilogue gather) ----
__global__ void k_prep(const float* __restrict__ emb, char* __restrict__ esw,
                       char* __restrict__ efp8, float* __restrict__ e2h) {
  const int tid = threadIdx.x;
  const int row = blockIdx.x * 32 + (tid >> 3);   // 0..8191
  const int seg = tid & 7;                        // 16-dim segment
  const int c = row >> 11, code = row & 2047;
  const float* src = emb + (size_t)row * DR + seg * 16;
  float v[16];
#pragma unroll
  for (int i = 0; i < 16; i += 4) {
    float4 t = *(const float4*)(src + i);
    v[i] = t.x; v[i+1] = t.y; v[i+2] = t.z; v[i+3] = t.w;
  }
  float s2 = 0.f;
#pragma unroll
  for (int i = 0; i < 16; ++i) s2 += v[i] * v[i];
  s2 += __shfl_down(s2, 4, 64);
  s2 += __shfl_down(s2, 2, 64);
  s2 += __shfl_down(s2, 1, 64);
  if (seg == 0) e2h[row] = BIAS - 2048.0f * s2;

  float vs[16];
#pragma unroll
  for (int i = 0; i < 16; ++i) vs[i] = v[i] * 4096.0f;
  i64x2 p; p.x = pack8_fp8(vs); p.y = pack8_fp8(vs + 8);
  *(i64x2*)(efp8 + (size_t)row * DR + seg * 16) = p;   // row-major fp8 image

  // fragment-order: this thread's 16 dims are one (lane,plane) 16B slot
  const int stage = code >> 6, cb = (code >> 4) & 3;
  const int g = seg >> 1, plane = seg & 1;
  const int lane = g * 16 + (code & 15);
  char* dst = esw + ((size_t)(c * 32 + stage) * 8192) + cb * 2048 + plane * 1024 + lane * 16;
  *(i64x2*)dst = p;
}

// ---- main: MX fp8 K=128 GEMM-argmax, code-split across wave pairs, lean registers ----
// chunk = 32 codes (half a stage): B = 2 x i32x8 (16 VGPR), double-buffered -> 32 VGPR
__device__ __forceinline__ void load_chunk(const char* bp, const float* e2p, int ch,
                                           i32x8& Ba, i32x8& Bb, float& ea, float& eb) {
  const char* p = bp + (size_t)ch * 4096;
  union { uint4 q[2]; i32x8 v; } ua, ub;
  ua.q[0] = *(const uint4*)p;
  ua.q[1] = *(const uint4*)(p + 1024);
  ub.q[0] = *(const uint4*)(p + 2048);
  ub.q[1] = *(const uint4*)(p + 3072);
  Ba = ua.v; Bb = ub.v;
  ea = e2p[ch * 32];
  eb = e2p[ch * 32 + 16];
}

__device__ __forceinline__ void compute_chunk(int ch, int r, const i32x8 A[4],
                                              const i32x8& Ba, const i32x8& Bb,
                                              float ea, float eb, u32 kk[4][4]) {
  const u32 inva = 2047u - (u32)(ch * 32 + r);
  const u32 invb = inva - 16u;
  f32x4 cia = {ea, ea, ea, ea}, cib = {eb, eb, eb, eb};
#pragma unroll
  for (int t2 = 0; t2 < 4; ++t2) {
    f32x4 a1 = __builtin_amdgcn_mfma_scale_f32_16x16x128_f8f6f4(
        A[t2], Ba, cia, 0, 0, 0, 0x7F7F7F7F, 0, 0x7F7F7F7F);
#pragma unroll
    for (int j = 0; j < 4; ++j) {
      u32 k = (__float_as_uint(a1[j]) & 0xFFFFF800u) | inva;
      kk[t2][j] = k > kk[t2][j] ? k : kk[t2][j];
    }
    f32x4 a2 = __builtin_amdgcn_mfma_scale_f32_16x16x128_f8f6f4(
        A[t2], Bb, cib, 0, 0, 0, 0x7F7F7F7F, 0, 0x7F7F7F7F);
#pragma unroll
    for (int j = 0; j < 4; ++j) {
      u32 k = (__float_as_uint(a2[j]) & 0xFFFFF800u) | invb;
      kk[t2][j] = k > kk[t2][j] ? k : kk[t2][j];
    }
  }
}

__launch_bounds__(256, 2)
__global__ void k_main(const float* __restrict__ lat,
                       const char* __restrict__ esw,
                       const char* __restrict__ efp8,
                       const float* __restrict__ e2h,
                       float* __restrict__ outq,
                       float* __restrict__ partials) {
  __shared__ u32 kbuf[4][64];
  __shared__ float x2buf[128];
  __shared__ int idxs[128];
  __shared__ float wsum[4];

  const int tid = threadIdx.x, wave = tid >> 6, lane = tid & 63;
  const int r = lane & 15, g = lane >> 4;
  const int pair = wave >> 1;          // token half: 0 -> tokens 0-63, 1 -> 64-127
  const int half = wave & 1;           // code half: 0 -> chunks 0-31, 1 -> 32-63
  const int bid = blockIdx.x;
  const int c = bid >> 8, b = (bid >> 3) & 31, hw0 = (bid & 7) * 128;

  const char* bp   = esw + (size_t)c * (NSTG * 8192) + lane * 16;
  const float* e2p = e2h + c * NK + r;
  const int ch0 = half * 32;

  // issue first B chunk (L2), then A loads (HBM) under it
  i32x8 Ba0, Bb0, Ba1, Bb1;
  float ea0, eb0, ea1, eb1;
  load_chunk(bp, e2p, ch0, Ba0, Bb0, ea0, eb0);

  // A: 64 tokens/wave as 4 tiles; lane (r,g) holds dims g*32..g*32+31, fp8-packed.
  // Also compute exact f32 ||x||^2 per token (for the key-based loss).
  i32x8 A[4];
  {
    const float* xb = lat + ((size_t)(b * 512 + c + g * 32)) * HW + hw0 + pair * 64 + r;
#pragma unroll
    for (int t2 = 0; t2 < 4; ++t2) {
      float xs[32];
#pragma unroll
      for (int j = 0; j < 32; ++j) xs[j] = xb[(size_t)j * HW + t2 * 16];
      union { long l[4]; i32x8 v; } u;
#pragma unroll
      for (int q = 0; q < 4; ++q) u.l[q] = pack8_fp8(xs + q * 8);
      A[t2] = u.v;
      float s = 0.f;
#pragma unroll
      for (int j = 0; j < 32; ++j) s += xs[j] * xs[j];
      s += __shfl_xor(s, 16, 64);
      s += __shfl_xor(s, 32, 64);        // all 4 g-lanes now hold token (pair*64+t2*16+r)'s ||x||^2
      if (half == 0 && g == 0) x2buf[pair * 64 + t2 * 16 + r] = s;
    }
  }

  u32 kk[4][4];
#pragma unroll
  for (int t2 = 0; t2 < 4; ++t2)
#pragma unroll
    for (int j = 0; j < 4; ++j) kk[t2][j] = 0u;

  // register-double-buffered loop over this wave's 32 chunks: no barriers
  for (int t = 0; t < 16; ++t) {
    const int s0 = ch0 + 2 * t;
    load_chunk(bp, e2p, s0 + 1, Ba1, Bb1, ea1, eb1);
    compute_chunk(s0, r, A, Ba0, Bb0, ea0, eb0, kk);
    if (t < 15) load_chunk(bp, e2p, s0 + 2, Ba0, Bb0, ea0, eb0);
    compute_chunk(s0 + 1, r, A, Ba1, Bb1, ea1, eb1, kk);
  }

  // cross-lane key-max over the 16 code lanes; index in low 11 bits
#pragma unroll
  for (int t2 = 0; t2 < 4; ++t2)
#pragma unroll
    for (int j = 0; j < 4; ++j) {
      u32 k = kk[t2][j];
#pragma unroll
      for (int m = 1; m < 16; m <<= 1) {
        u32 o = (u32)__shfl_xor((int)k, m, 64);
        if (o > k) k = o;
      }
      if (r == 0) kbuf[wave][t2 * 16 + g * 4 + j] = k;
    }
  __syncthreads();

  // combine code halves per token; loss from key: 2048*dist = (BIAS - score) + 2048*||x||^2
  float lossv = 0.f;
  if (tid < 128) {
    const int p = tid >> 6, m = tid & 63;
    u32 ka = kbuf[2 * p][m], kb = kbuf[2 * p + 1][m];
    u32 k = ka > kb ? ka : kb;
    idxs[tid] = 2047 - (int)(k & 2047u);
    float kf = __uint_as_float(k & 0xFFFFF800u);
    lossv = (BIAS - kf) + 2048.0f * x2buf[tid];
  }
#pragma unroll
  for (int off = 32; off; off >>= 1) lossv += __shfl_down(lossv, off, 64);
  if (lane == 0) wsum[wave] = lossv;
  __syncthreads();
  if (tid == 0) partials[bid] = wsum[0] + wsum[1] + wsum[2] + wsum[3];

  // epilogue: fp8 gather (16B/row-seg), dequant, coalesced write (no lat re-read)
  const int q5 = tid & 31, dg = tid >> 5;       // 32 token-quads x 8 dim-groups of 16
  const int tok0 = q5 * 4;
  const int code0 = idxs[tok0], code1 = idxs[tok0 + 1], code2 = idxs[tok0 + 2], code3 = idxs[tok0 + 3];
  const char* eb = efp8 + (size_t)c * NK * DR + dg * 16;
  uint4 e0 = *(const uint4*)(eb + (size_t)code0 * DR);
  uint4 e1 = *(const uint4*)(eb + (size_t)code1 * DR);
  uint4 e2v = *(const uint4*)(eb + (size_t)code2 * DR);
  uint4 e3 = *(const uint4*)(eb + (size_t)code3 * DR);
  float* orow = outq + ((size_t)(b * 512 + c * DR + dg * 16)) * HW + hw0 + tok0;
  const float SINV = 1.0f / 4096.0f;

#define WORD(v, w) ((w) == 0 ? (v).x : (w) == 1 ? (v).y : (w) == 2 ? (v).z : (v).w)
#pragma unroll
  for (int w = 0; w < 4; ++w) {
    f32x2 lo0 = __builtin_amdgcn_cvt_pk_f32_fp8((int)WORD(e0, w), false);
    f32x2 hi0 = __builtin_amdgcn_cvt_pk_f32_fp8((int)WORD(e0, w), true);
    f32x2 lo1 = __builtin_amdgcn_cvt_pk_f32_fp8((int)WORD(e1, w), false);
    f32x2 hi1 = __builtin_amdgcn_cvt_pk_f32_fp8((int)WORD(e1, w), true);
    f32x2 lo2 = __builtin_amdgcn_cvt_pk_f32_fp8((int)WORD(e2v, w), false);
    f32x2 hi2 = __builtin_amdgcn_cvt_pk_f32_fp8((int)WORD(e2v, w), true);
    f32x2 lo3 = __builtin_amdgcn_cvt_pk_f32_fp8((int)WORD(e3, w), false);
    f32x2 hi3 = __builtin_amdgcn_cvt_pk_f32_fp8((int)WORD(e3, w), true);
    float f0[4] = {lo0.x, lo0.y, hi0.x, hi0.y};
    float f1[4] = {lo1.x, lo1.y, hi1.x, hi1.y};
    float f2[4] = {lo2.x, lo2.y, hi2.x, hi2.y};
    float f3[4] = {lo3.x, lo3.y, hi3.x, hi3.y};
#pragma unroll
    for (int dd = 0; dd < 4; ++dd) {
      int d = w * 4 + dd;
      float4 qv = {f0[dd] * SINV, f1[dd] * SINV, f2[dd] * SINV, f3[dd] * SINV};
      *(float4*)(orow + (size_t)d * HW) = qv;
    }
  }
#undef WORD
}

// ---- final: reduce 1024 partials -> vq_loss (partials carry 2048*dist) ----
__global__ void k_final(const float* __restrict__ partials, float* __restrict__ out_scalar) {
  __shared__ float ws[4];
  int tid = threadIdx.x;
  float s = partials[tid] + partials[tid + 256] + partials[tid + 512] + partials[tid + 768];
#pragma unroll
  for (int off = 32; off; off >>= 1) s += __shfl_down(s, off, 64);
  if ((tid & 63) == 0) ws[tid >> 6] = s;
  __syncthreads();
  if (tid == 0) out_scalar[0] = (ws[0] + ws[1] + ws[2] + ws[3]) * (1.25f / 8589934592.0f);
}

extern "C" void kernel_launch(void* const* d_in, const int* in_sizes, int n_in,
                              void* d_out, int out_size, void* d_ws, size_t ws_size,
                              hipStream_t stream) {
  const float* lat = (const float*)d_in[0];   // [32,512,32,32] f32
  const float* emb = (const float*)d_in[1];   // [4,2048,128] f32
  float* out = (float*)d_out;                 // quantized (16777216) + loss (1)

  char*  esw      = (char*)d_ws;                                   // 1 MB fragment-order fp8
  char*  efp8     = (char*)d_ws + (1u << 20);                      // 1 MB row-major fp8
  float* e2h      = (float*)((char*)d_ws + (2u << 20));            // 32 KB
  float* partials = (float*)((char*)d_ws + (2u << 20) + 32768u);   // 4 KB

  k_prep <<<dim3(256),  dim3(256), 0, stream>>>(emb, esw, efp8, e2h);
  k_main <<<dim3(1024), dim3(256), 0, stream>>>(lat, esw, efp8, e2h, out, partials);
  k_final<<<dim3(1),    dim3(256), 0, stream>>>(partials, out + 16777216);
}

// Round 8
// 60.744 us; speedup vs baseline: 4.5071x; 1.0463x over previous
//
#include <hip/hip_runtime.h>
#include <stdint.h>

#define HW    1024          // H*W
#define NK    2048          // codes per codebook
#define DR    128           // reduced dim
#define NSTG  32            // stages of 64 codes
#define BIAS  1536.0f       // score positivity bias (scores stay in one binade [1024,2048))

typedef __attribute__((ext_vector_type(4))) float f32x4;
typedef __attribute__((ext_vector_type(2))) float f32x2;
typedef __attribute__((ext_vector_type(2))) long i64x2;
typedef __attribute__((ext_vector_type(8))) int i32x8;
typedef unsigned int u32;
typedef unsigned long long u64;

__device__ __forceinline__ long pack8_fp8(const float* x) {
  int lo = 0, hi = 0;
  lo = __builtin_amdgcn_cvt_pk_fp8_f32(x[0], x[1], lo, false);
  lo = __builtin_amdgcn_cvt_pk_fp8_f32(x[2], x[3], lo, true);
  hi = __builtin_amdgcn_cvt_pk_fp8_f32(x[4], x[5], hi, false);
  hi = __builtin_amdgcn_cvt_pk_fp8_f32(x[6], x[7], hi, true);
  return (long)(u32)lo | ((long)hi << 32);
}

// ---- prep (fused): e2h = BIAS - 2048*sum(e^2); esw = K128-fragment-order fp8*4096;
//      efp8 = row-major fp8*4096 (epilogue gather) ----
__global__ void k_prep(const float* __restrict__ emb, char* __restrict__ esw,
                       char* __restrict__ efp8, float* __restrict__ e2h) {
  const int tid = threadIdx.x;
  const int row = blockIdx.x * 32 + (tid >> 3);   // 0..8191
  const int seg = tid & 7;                        // 16-dim segment
  const int c = row >> 11, code = row & 2047;
  const float* src = emb + (size_t)row * DR + seg * 16;
  float v[16];
#pragma unroll
  for (int i = 0; i < 16; i += 4) {
    float4 t = *(const float4*)(src + i);
    v[i] = t.x; v[i+1] = t.y; v[i+2] = t.z; v[i+3] = t.w;
  }
  float s2 = 0.f;
#pragma unroll
  for (int i = 0; i < 16; ++i) s2 += v[i] * v[i];
  s2 += __shfl_down(s2, 4, 64);
  s2 += __shfl_down(s2, 2, 64);
  s2 += __shfl_down(s2, 1, 64);
  if (seg == 0) e2h[row] = BIAS - 2048.0f * s2;

  float vs[16];
#pragma unroll
  for (int i = 0; i < 16; ++i) vs[i] = v[i] * 4096.0f;
  i64x2 p; p.x = pack8_fp8(vs); p.y = pack8_fp8(vs + 8);
  *(i64x2*)(efp8 + (size_t)row * DR + seg * 16) = p;   // row-major fp8 image

  // fragment-order: this thread's 16 dims are one (lane,plane) 16B slot
  const int stage = code >> 6, cb = (code >> 4) & 3;
  const int g = seg >> 1, plane = seg & 1;
  const int lane = g * 16 + (code & 15);
  char* dst = esw + ((size_t)(c * 32 + stage) * 8192) + cb * 2048 + plane * 1024 + lane * 16;
  *(i64x2*)dst = p;
}

// ---- main: MX fp8 K=128 GEMM-argmax, 16-code chunks, depth-3 register pipeline ----
__device__ __forceinline__ void load_c16(const char* bp, const float* e2p, int ch,
                                         i32x8& B, float& e2) {
  const char* p = bp + (size_t)ch * 2048;   // 16 codes x 128 dims fp8 = 2 KB
  union { uint4 q[2]; i32x8 v; } u;
  u.q[0] = *(const uint4*)p;
  u.q[1] = *(const uint4*)(p + 1024);
  B = u.v;
  e2 = e2p[ch * 16];
}

__device__ __forceinline__ void comp_c16(int ch, int r, const i32x8 A[4],
                                         const i32x8& B, float e2, u32 kk[4][4]) {
  const u32 inv = 2047u - (u32)(ch * 16 + r);
  f32x4 ci = {e2, e2, e2, e2};
#pragma unroll
  for (int t2 = 0; t2 < 4; ++t2) {
    f32x4 ac = __builtin_amdgcn_mfma_scale_f32_16x16x128_f8f6f4(
        A[t2], B, ci, 0, 0, 0, 0x7F7F7F7F, 0, 0x7F7F7F7F);
#pragma unroll
    for (int j = 0; j < 4; ++j) {
      u32 k = (__float_as_uint(ac[j]) & 0xFFFFF800u) | inv;
      kk[t2][j] = k > kk[t2][j] ? k : kk[t2][j];
    }
  }
}

__launch_bounds__(256, 2)
__global__ void k_main(const float* __restrict__ lat,
                       const char* __restrict__ esw,
                       const char* __restrict__ efp8,
                       const float* __restrict__ e2h,
                       float* __restrict__ outq,
                       float* __restrict__ partials) {
  __shared__ u32 kbuf[4][64];
  __shared__ float x2buf[128];
  __shared__ int idxs[128];
  __shared__ float wsum[4];

  const int tid = threadIdx.x, wave = tid >> 6, lane = tid & 63;
  const int r = lane & 15, g = lane >> 4;
  const int pair = wave >> 1;          // token half: 0 -> tokens 0-63, 1 -> 64-127
  const int half = wave & 1;           // code half: 0 -> chunks 0-63, 1 -> 64-127
  const int bid = blockIdx.x;
  const int c = bid >> 8, b = (bid >> 3) & 31, hw0 = (bid & 7) * 128;

  const char* bp   = esw + (size_t)c * (NSTG * 8192) + lane * 16;
  const float* e2p = e2h + c * NK + r;
  const int ch0 = half * 64, chN = ch0 + 63;

  // prologue: 3 chunk loads in flight (L2), then A loads (HBM) beneath them
  i32x8 P0, P1, P2, P3;
  float E0, E1, E2, E3;
  load_c16(bp, e2p, ch0 + 0, P0, E0);
  load_c16(bp, e2p, ch0 + 1, P1, E1);
  load_c16(bp, e2p, ch0 + 2, P2, E2);

  // A: 64 tokens/wave as 4 tiles; lane (r,g) holds dims g*32..g*32+31, fp8-packed.
  // Also exact f32 ||x||^2 per token (for the key-based loss).
  i32x8 A[4];
  {
    const float* xb = lat + ((size_t)(b * 512 + c + g * 32)) * HW + hw0 + pair * 64 + r;
#pragma unroll
    for (int t2 = 0; t2 < 4; ++t2) {
      float xs[32];
#pragma unroll
      for (int j = 0; j < 32; ++j) xs[j] = xb[(size_t)j * HW + t2 * 16];
      union { long l[4]; i32x8 v; } u;
#pragma unroll
      for (int q = 0; q < 4; ++q) u.l[q] = pack8_fp8(xs + q * 8);
      A[t2] = u.v;
      float s = 0.f;
#pragma unroll
      for (int j = 0; j < 32; ++j) s += xs[j] * xs[j];
      s += __shfl_xor(s, 16, 64);
      s += __shfl_xor(s, 32, 64);
      if (half == 0 && g == 0) x2buf[pair * 64 + t2 * 16 + r] = s;
    }
  }

  u32 kk[4][4];
#pragma unroll
  for (int t2 = 0; t2 < 4; ++t2)
#pragma unroll
    for (int j = 0; j < 4; ++j) kk[t2][j] = 0u;

  // depth-3 pipeline over 64 chunks: every load issued 3 chunk-computes before use
  for (int t = 0; t < 16; ++t) {
    const int base = ch0 + 4 * t;
    int n3 = base + 3 > chN ? chN : base + 3;
    load_c16(bp, e2p, n3, P3, E3);
    comp_c16(base + 0, r, A, P0, E0, kk);
    int n4 = base + 4 > chN ? chN : base + 4;
    load_c16(bp, e2p, n4, P0, E0);
    comp_c16(base + 1, r, A, P1, E1, kk);
    int n5 = base + 5 > chN ? chN : base + 5;
    load_c16(bp, e2p, n5, P1, E1);
    comp_c16(base + 2, r, A, P2, E2, kk);
    int n6 = base + 6 > chN ? chN : base + 6;
    load_c16(bp, e2p, n6, P2, E2);
    comp_c16(base + 3, r, A, P3, E3, kk);
  }

  // cross-lane key-max over the 16 code lanes; index in low 11 bits
#pragma unroll
  for (int t2 = 0; t2 < 4; ++t2)
#pragma unroll
    for (int j = 0; j < 4; ++j) {
      u32 k = kk[t2][j];
#pragma unroll
      for (int m = 1; m < 16; m <<= 1) {
        u32 o = (u32)__shfl_xor((int)k, m, 64);
        if (o > k) k = o;
      }
      if (r == 0) kbuf[wave][t2 * 16 + g * 4 + j] = k;
    }
  __syncthreads();

  // combine code halves per token; loss from key: 2048*dist = (BIAS - score) + 2048*||x||^2
  float lossv = 0.f;
  if (tid < 128) {
    const int p = tid >> 6, m = tid & 63;
    u32 ka = kbuf[2 * p][m], kb = kbuf[2 * p + 1][m];
    u32 k = ka > kb ? ka : kb;
    idxs[tid] = 2047 - (int)(k & 2047u);
    float kf = __uint_as_float(k & 0xFFFFF800u);
    lossv = (BIAS - kf) + 2048.0f * x2buf[tid];
  }
#pragma unroll
  for (int off = 32; off; off >>= 1) lossv += __shfl_down(lossv, off, 64);
  if (lane == 0) wsum[wave] = lossv;
  __syncthreads();
  if (tid == 0) partials[bid] = wsum[0] + wsum[1] + wsum[2] + wsum[3];

  // epilogue: fp8 gather (16B/row-seg), dequant, coalesced write (no lat re-read)
  const int q5 = tid & 31, dg = tid >> 5;       // 32 token-quads x 8 dim-groups of 16
  const int tok0 = q5 * 4;
  const int code0 = idxs[tok0], code1 = idxs[tok0 + 1], code2 = idxs[tok0 + 2], code3 = idxs[tok0 + 3];
  const char* eb = efp8 + (size_t)c * NK * DR + dg * 16;
  uint4 e0 = *(const uint4*)(eb + (size_t)code0 * DR);
  uint4 e1 = *(const uint4*)(eb + (size_t)code1 * DR);
  uint4 e2v = *(const uint4*)(eb + (size_t)code2 * DR);
  uint4 e3 = *(const uint4*)(eb + (size_t)code3 * DR);
  float* orow = outq + ((size_t)(b * 512 + c * DR + dg * 16)) * HW + hw0 + tok0;
  const float SINV = 1.0f / 4096.0f;

#define WORD(v, w) ((w) == 0 ? (v).x : (w) == 1 ? (v).y : (w) == 2 ? (v).z : (v).w)
#pragma unroll
  for (int w = 0; w < 4; ++w) {
    f32x2 lo0 = __builtin_amdgcn_cvt_pk_f32_fp8((int)WORD(e0, w), false);
    f32x2 hi0 = __builtin_amdgcn_cvt_pk_f32_fp8((int)WORD(e0, w), true);
    f32x2 lo1 = __builtin_amdgcn_cvt_pk_f32_fp8((int)WORD(e1, w), false);
    f32x2 hi1 = __builtin_amdgcn_cvt_pk_f32_fp8((int)WORD(e1, w), true);
    f32x2 lo2 = __builtin_amdgcn_cvt_pk_f32_fp8((int)WORD(e2v, w), false);
    f32x2 hi2 = __builtin_amdgcn_cvt_pk_f32_fp8((int)WORD(e2v, w), true);
    f32x2 lo3 = __builtin_amdgcn_cvt_pk_f32_fp8((int)WORD(e3, w), false);
    f32x2 hi3 = __builtin_amdgcn_cvt_pk_f32_fp8((int)WORD(e3, w), true);
    float f0[4] = {lo0.x, lo0.y, hi0.x, hi0.y};
    float f1[4] = {lo1.x, lo1.y, hi1.x, hi1.y};
    float f2[4] = {lo2.x, lo2.y, hi2.x, hi2.y};
    float f3[4] = {lo3.x, lo3.y, hi3.x, hi3.y};
#pragma unroll
    for (int dd = 0; dd < 4; ++dd) {
      int d = w * 4 + dd;
      float4 qv = {f0[dd] * SINV, f1[dd] * SINV, f2[dd] * SINV, f3[dd] * SINV};
      *(float4*)(orow + (size_t)d * HW) = qv;
    }
  }
#undef WORD
}

// ---- final: reduce 1024 partials -> vq_loss (partials carry 2048*dist) ----
__global__ void k_final(const float* __restrict__ partials, float* __restrict__ out_scalar) {
  __shared__ float ws[4];
  int tid = threadIdx.x;
  float s = partials[tid] + partials[tid + 256] + partials[tid + 512] + partials[tid + 768];
#pragma unroll
  for (int off = 32; off; off >>= 1) s += __shfl_down(s, off, 64);
  if ((tid & 63) == 0) ws[tid >> 6] = s;
  __syncthreads();
  if (tid == 0) out_scalar[0] = (ws[0] + ws[1] + ws[2] + ws[3]) * (1.25f / 8589934592.0f);
}

extern "C" void kernel_launch(void* const* d_in, const int* in_sizes, int n_in,
                              void* d_out, int out_size, void* d_ws, size_t ws_size,
                              hipStream_t stream) {
  const float* lat = (const float*)d_in[0];   // [32,512,32,32] f32
  const float* emb = (const float*)d_in[1];   // [4,2048,128] f32
  float* out = (float*)d_out;                 // quantized (16777216) + loss (1)

  char*  esw      = (char*)d_ws;                                   // 1 MB fragment-order fp8
  char*  efp8     = (char*)d_ws + (1u << 20);                      // 1 MB row-major fp8
  float* e2h      = (float*)((char*)d_ws + (2u << 20));            // 32 KB
  float* partials = (float*)((char*)d_ws + (2u << 20) + 32768u);   // 4 KB

  k_prep <<<dim3(256),  dim3(256), 0, stream>>>(emb, esw, efp8, e2h);
  k_main <<<dim3(1024), dim3(256), 0, stream>>>(lat, esw, efp8, e2h, out, partials);
  k_final<<<dim3(1),    dim3(256), 0, stream>>>(partials, out + 16777216);
}